// Round 1
// baseline (13071.429 us; speedup 1.0000x reference)
//
#include <hip/hip_runtime.h>

#define TT 512
#define BB 32
#define II 512
#define HH 1024
#define G3 3072
#define TBH (TT * BB * HH) /* 16777216 */

__device__ __forceinline__ float sigmoidf_(float x) {
    return 1.f / (1.f + __expf(-x));
}
__device__ __forceinline__ float tanh_fast(float x) {
    float e2 = __expf(2.f * x);
    return 1.f - 2.f / (e2 + 1.f); /* safe at +/-inf */
}

/* ---- w_hh (1024 x 3072) -> wT (3072 x 1024) ---- */
__global__ __launch_bounds__(256) void k_transpose(const float* __restrict__ w,
                                                   float* __restrict__ wT) {
    __shared__ float tile[32][33];
    int tx = threadIdx.x, ty = threadIdx.y;
    int c0 = blockIdx.x * 32, k0 = blockIdx.y * 32;
#pragma unroll
    for (int i = 0; i < 4; ++i)
        tile[ty + i * 8][tx] = w[(size_t)(k0 + ty + i * 8) * G3 + c0 + tx];
    __syncthreads();
#pragma unroll
    for (int i = 0; i < 4; ++i)
        wT[(size_t)(c0 + ty + i * 8) * HH + k0 + tx] = tile[tx][ty + i * 8];
}

/* ---- gi = A(M x 512) @ w_ih(512 x 3072) + b_ih ---- */
__global__ __launch_bounds__(256) void k_gi_gemm(const float* __restrict__ A,
                                                 const float* __restrict__ B,
                                                 const float* __restrict__ bias,
                                                 float* __restrict__ C, int M) {
    __shared__ float As[8][128];
    __shared__ float Bs[8][128];
    int tid = threadIdx.x;
    int m0 = blockIdx.x * 128;
    int n0 = blockIdx.y * 128;
    int tx = tid & 15, ty = tid >> 4;
    int rowA = tid >> 1, kA = (tid & 1) * 4;
    int kB = tid >> 5, cB = (tid & 31) * 4;
    float acc[8][8] = {};
    for (int k0 = 0; k0 < 512; k0 += 8) {
        int rg = m0 + rowA;
        if (rg > M - 1) rg = M - 1;
        float4 a4 = *(const float4*)(A + (size_t)rg * 512 + k0 + kA);
        float4 b4 = *(const float4*)(B + (size_t)(k0 + kB) * G3 + n0 + cB);
        __syncthreads();
        As[kA + 0][rowA] = a4.x;
        As[kA + 1][rowA] = a4.y;
        As[kA + 2][rowA] = a4.z;
        As[kA + 3][rowA] = a4.w;
        *(float4*)&Bs[kB][cB] = b4;
        __syncthreads();
#pragma unroll
        for (int kk = 0; kk < 8; ++kk) {
            float4 a0 = *(const float4*)&As[kk][ty * 8];
            float4 a1 = *(const float4*)&As[kk][ty * 8 + 4];
            float4 b0 = *(const float4*)&Bs[kk][tx * 8];
            float4 b1 = *(const float4*)&Bs[kk][tx * 8 + 4];
            float av[8] = {a0.x, a0.y, a0.z, a0.w, a1.x, a1.y, a1.z, a1.w};
            float bv[8] = {b0.x, b0.y, b0.z, b0.w, b1.x, b1.y, b1.z, b1.w};
#pragma unroll
            for (int i = 0; i < 8; ++i)
#pragma unroll
                for (int j = 0; j < 8; ++j) acc[i][j] += av[i] * bv[j];
        }
    }
    float4 bi0 = *(const float4*)(bias + n0 + tx * 8);
    float4 bi1 = *(const float4*)(bias + n0 + tx * 8 + 4);
    float bb[8] = {bi0.x, bi0.y, bi0.z, bi0.w, bi1.x, bi1.y, bi1.z, bi1.w};
#pragma unroll
    for (int i = 0; i < 8; ++i) {
        int row = m0 + ty * 8 + i;
        if (row < M) {
            float4 s0 = {acc[i][0] + bb[0], acc[i][1] + bb[1], acc[i][2] + bb[2], acc[i][3] + bb[3]};
            float4 s1 = {acc[i][4] + bb[4], acc[i][5] + bb[5], acc[i][6] + bb[6], acc[i][7] + bb[7]};
            *(float4*)(C + (size_t)row * G3 + n0 + tx * 8) = s0;
            *(float4*)(C + (size_t)row * G3 + n0 + tx * 8 + 4) = s1;
        }
    }
}

/* ---- one recurrent step ----
   grid 1024 = 256 j-quads x 4 batch-octets; block 256 thr = 4 waves.
   wave -> one j-triple (j, j+H, j+2H) x 8 batches; lane -> k-chunk [lane*16, +16). */
__global__ __launch_bounds__(256) void k_step(const float* __restrict__ wT,
                                              const float* __restrict__ gi,
                                              const float* __restrict__ pad,
                                              const float* __restrict__ b_hh,
                                              const float* __restrict__ h_in,
                                              float* __restrict__ h_out,
                                              float* __restrict__ out, int t, int tl) {
    int tid = threadIdx.x;
    int lane = tid & 63, wave = tid >> 6;
    int jq = blockIdx.x & 255, oct = blockIdx.x >> 8;
    int j = jq * 4 + wave;
    int b0 = oct * 8;

    const float* wr_p = wT + (size_t)j * HH + lane * 16;
    const float* wz_p = wT + (size_t)(j + HH) * HH + lane * 16;
    const float* wn_p = wT + (size_t)(j + 2 * HH) * HH + lane * 16;
    float4 wr[4], wz[4], wn[4];
#pragma unroll
    for (int i = 0; i < 4; ++i) {
        wr[i] = *(const float4*)(wr_p + i * 4);
        wz[i] = *(const float4*)(wz_p + i * 4);
        wn[i] = *(const float4*)(wn_p + i * 4);
    }

    /* lane-parallel preload of per-(b) scalars: gi r/z/n, h_prev, padding */
    float pre = 0.f;
    if (lane < 24)
        pre = gi[(size_t)(tl * BB + b0 + (lane & 7)) * G3 + (lane >> 3) * HH + j];
    else if (lane < 32)
        pre = h_in[(size_t)(b0 + (lane - 24)) * HH + j];
    else if (lane < 40)
        pre = pad[t * BB + b0 + (lane - 32)];

    float bhr = b_hh[j], bhz = b_hh[j + HH], bhn = b_hh[j + 2 * HH];

    float keep = 0.f;
    for (int b = 0; b < 8; ++b) {
        const float* hp = h_in + (size_t)(b0 + b) * HH + lane * 16;
        float ar = 0.f, az = 0.f, an = 0.f;
#pragma unroll
        for (int i = 0; i < 4; ++i) {
            float4 h4 = *(const float4*)(hp + i * 4);
            ar += h4.x * wr[i].x + h4.y * wr[i].y + h4.z * wr[i].z + h4.w * wr[i].w;
            az += h4.x * wz[i].x + h4.y * wz[i].y + h4.z * wz[i].z + h4.w * wz[i].w;
            an += h4.x * wn[i].x + h4.y * wn[i].y + h4.z * wn[i].z + h4.w * wn[i].w;
        }
#pragma unroll
        for (int m = 1; m < 64; m <<= 1) {
            ar += __shfl_xor(ar, m);
            az += __shfl_xor(az, m);
            an += __shfl_xor(an, m);
        }
        float gir = __shfl(pre, b);
        float giz = __shfl(pre, 8 + b);
        float gin = __shfl(pre, 16 + b);
        float hprev = __shfl(pre, 24 + b);
        float p = __shfl(pre, 32 + b);
        float r = sigmoidf_(gir + ar + bhr);
        float z = sigmoidf_(giz + az + bhz);
        float n = tanh_fast(gin + r * (an + bhn));
        float hnew = (1.f - z) * n + z * hprev;
        hnew = p * hprev + (1.f - p) * hnew;
        if (lane == b) keep = hnew;
    }
    if (lane < 8) {
        int bg = b0 + lane;
        size_t o = (size_t)bg * HH + j;
        h_out[o] = keep;
        size_t oo = (size_t)t * (BB * HH) + o;
        out[oo] = keep;
        out[(size_t)TBH + oo] = keep;
    }
}

/* ---- emergency fallback if workspace is tiny: fused, slow, correct ---- */
__global__ __launch_bounds__(256) void k_step_slow(const float* __restrict__ x_t,
                                                   const float* __restrict__ pad_t,
                                                   const float* __restrict__ w_ih,
                                                   const float* __restrict__ w_hh,
                                                   const float* __restrict__ b_ih,
                                                   const float* __restrict__ b_hh,
                                                   const float* __restrict__ h_in,
                                                   float* __restrict__ h_out,
                                                   float* __restrict__ out, int t) {
    int g = blockIdx.x * 256 + threadIdx.x; /* 32768 threads */
    int b = g >> 10, j = g & 1023;
    float gir = b_ih[j], giz = b_ih[j + HH], gin = b_ih[j + 2 * HH];
    for (int k = 0; k < II; ++k) {
        float xv = x_t[b * II + k];
        const float* wr = w_ih + (size_t)k * G3;
        gir += xv * wr[j];
        giz += xv * wr[j + HH];
        gin += xv * wr[j + 2 * HH];
    }
    float ghr = b_hh[j], ghz = b_hh[j + HH], ghn = b_hh[j + 2 * HH];
    for (int k = 0; k < HH; ++k) {
        float hv = h_in[b * HH + k];
        const float* wr = w_hh + (size_t)k * G3;
        ghr += hv * wr[j];
        ghz += hv * wr[j + HH];
        ghn += hv * wr[j + 2 * HH];
    }
    float hprev = h_in[b * HH + j];
    float p = pad_t[b];
    float r = sigmoidf_(gir + ghr);
    float z = sigmoidf_(giz + ghz);
    float n = tanh_fast(gin + r * ghn);
    float hnew = (1.f - z) * n + z * hprev;
    hnew = p * hprev + (1.f - p) * hnew;
    size_t o = (size_t)b * HH + j;
    h_out[o] = hnew;
    size_t oo = (size_t)t * (BB * HH) + o;
    out[oo] = hnew;
    out[(size_t)TBH + oo] = hnew;
}

extern "C" void kernel_launch(void* const* d_in, const int* in_sizes, int n_in,
                              void* d_out, int out_size, void* d_ws, size_t ws_size,
                              hipStream_t stream) {
    const float* x    = (const float*)d_in[0];
    const float* pad  = (const float*)d_in[1];
    const float* w_ih = (const float*)d_in[2];
    const float* w_hh = (const float*)d_in[3];
    const float* b_ih = (const float*)d_in[4];
    const float* b_hh = (const float*)d_in[5];
    float* out = (float*)d_out;

    char* wsb = (char*)d_ws;
    float* hA = (float*)wsb;                  /* 128 KB */
    float* hB = (float*)(wsb + 131072);       /* 128 KB */
    float* wT = (float*)(wsb + 262144);       /* 12.58 MB */
    float* gi = (float*)(wsb + 12845056);     /* Tc * 32 * 3072 * 4 B */

    long long cap = (long long)ws_size - 12845056LL;
    int Tc = cap > 0 ? (int)(cap / 393216LL) : 0;
    if (Tc > TT) Tc = TT;

    hipMemsetAsync(hA, 0, 131072, stream); /* h(t=0) = 0 */

    if (Tc >= 1) {
        k_transpose<<<dim3(96, 32), dim3(32, 8), 0, stream>>>(w_hh, wT);
        for (int t0 = 0; t0 < TT; t0 += Tc) {
            int ct = (TT - t0 < Tc) ? (TT - t0) : Tc;
            int M = ct * BB;
            dim3 g((M + 127) / 128, 24);
            k_gi_gemm<<<g, 256, 0, stream>>>(x + (size_t)t0 * BB * II, w_ih, b_ih, gi, M);
            for (int k = 0; k < ct; ++k) {
                int t = t0 + k;
                const float* hin = (t & 1) ? hB : hA;
                float* hout = (t & 1) ? hA : hB;
                k_step<<<1024, 256, 0, stream>>>(wT, gi, pad, b_hh, hin, hout, out, t, k);
            }
        }
    } else {
        for (int t = 0; t < TT; ++t) {
            const float* hin = (t & 1) ? hB : hA;
            float* hout = (t & 1) ? hA : hB;
            k_step_slow<<<128, 256, 0, stream>>>(x + (size_t)t * BB * II, pad + t * BB,
                                                 w_ih, w_hh, b_ih, b_hh, hin, hout, out, t);
        }
    }
}

// Round 2
// 12742.928 us; speedup vs baseline: 1.0258x; 1.0258x over previous
//
#include <hip/hip_runtime.h>

#define TT 512
#define BB 32
#define II 512
#define HH 1024
#define G3 3072
#define TBH (TT * BB * HH) /* 16777216 */

__device__ __forceinline__ float sigmoidf_(float x) {
    return 1.f / (1.f + __expf(-x));
}
__device__ __forceinline__ float tanh_fast(float x) {
    float e2 = __expf(2.f * x);
    return 1.f - 2.f / (e2 + 1.f);
}

/* ---- gi = A(M x 512) @ w_ih(512 x 3072) + b_ih ---- */
__global__ __launch_bounds__(256) void k_gi_gemm(const float* __restrict__ A,
                                                 const float* __restrict__ B,
                                                 const float* __restrict__ bias,
                                                 float* __restrict__ C, int M) {
    __shared__ float As[8][128];
    __shared__ float Bs[8][128];
    int tid = threadIdx.x;
    int m0 = blockIdx.x * 128;
    int n0 = blockIdx.y * 128;
    int tx = tid & 15, ty = tid >> 4;
    int rowA = tid >> 1, kA = (tid & 1) * 4;
    int kB = tid >> 5, cB = (tid & 31) * 4;
    float acc[8][8] = {};
    for (int k0 = 0; k0 < 512; k0 += 8) {
        int rg = m0 + rowA;
        if (rg > M - 1) rg = M - 1;
        float4 a4 = *(const float4*)(A + (size_t)rg * 512 + k0 + kA);
        float4 b4 = *(const float4*)(B + (size_t)(k0 + kB) * G3 + n0 + cB);
        __syncthreads();
        As[kA + 0][rowA] = a4.x;
        As[kA + 1][rowA] = a4.y;
        As[kA + 2][rowA] = a4.z;
        As[kA + 3][rowA] = a4.w;
        *(float4*)&Bs[kB][cB] = b4;
        __syncthreads();
#pragma unroll
        for (int kk = 0; kk < 8; ++kk) {
            float4 a0 = *(const float4*)&As[kk][ty * 8];
            float4 a1 = *(const float4*)&As[kk][ty * 8 + 4];
            float4 b0 = *(const float4*)&Bs[kk][tx * 8];
            float4 b1 = *(const float4*)&Bs[kk][tx * 8 + 4];
            float av[8] = {a0.x, a0.y, a0.z, a0.w, a1.x, a1.y, a1.z, a1.w};
            float bv[8] = {b0.x, b0.y, b0.z, b0.w, b1.x, b1.y, b1.z, b1.w};
#pragma unroll
            for (int i = 0; i < 8; ++i)
#pragma unroll
                for (int j = 0; j < 8; ++j) acc[i][j] += av[i] * bv[j];
        }
    }
    float4 bi0 = *(const float4*)(bias + n0 + tx * 8);
    float4 bi1 = *(const float4*)(bias + n0 + tx * 8 + 4);
    float bb[8] = {bi0.x, bi0.y, bi0.z, bi0.w, bi1.x, bi1.y, bi1.z, bi1.w};
#pragma unroll
    for (int i = 0; i < 8; ++i) {
        int row = m0 + ty * 8 + i;
        if (row < M) {
            float4 s0 = {acc[i][0] + bb[0], acc[i][1] + bb[1], acc[i][2] + bb[2], acc[i][3] + bb[3]};
            float4 s1 = {acc[i][4] + bb[4], acc[i][5] + bb[5], acc[i][6] + bb[6], acc[i][7] + bb[7]};
            *(float4*)(C + (size_t)row * G3 + n0 + tx * 8) = s0;
            *(float4*)(C + (size_t)row * G3 + n0 + tx * 8 + 4) = s1;
        }
    }
}

/* ---- persistent recurrent kernel ----
   grid 256 = 64 h-col-groups x 4 batch-octets; block 512 thr = 8 waves.
   Block owns 16 h-cols (48 gate-cols, complete r/z/n triples) x 1024 k x 8 batches.
   Thread (cg in [0,16), ks in [0,32)): holds w[3][32] in VGPRs for its triple's
   k-slice [ks*32, ks*32+32). 94 KB LDS forces 1 block/CU -> all 256 co-resident. */
__global__ __launch_bounds__(512, 2) void k_persist(const float* __restrict__ w_hh,
                                                    const float* __restrict__ gi,
                                                    const float* __restrict__ pad,
                                                    const float* __restrict__ b_hh,
                                                    float* __restrict__ hA,
                                                    float* __restrict__ hB,
                                                    float* __restrict__ out,
                                                    unsigned* __restrict__ flags,
                                                    int t0, int ct) {
    __shared__ float h_s[9216];   /* [b 8][ks 32] chunks of 36 (32 + 4 pad) */
    __shared__ float part[13888]; /* [cg 16] stride 868: [(g,b) 24] stride 36: [ks 32] */
    __shared__ float sums[384];   /* [cg 16][ (g,b) 24 ] */

    int tid = threadIdx.x;
    int cg = tid & 15, ks = tid >> 4;
    int hg = blockIdx.x & 63, boct = blockIdx.x >> 6;
    int hc0 = hg << 4;
    int b0 = boct << 3;
    int col = hc0 + cg;

    /* one-time weight load: k-contiguous within 16-lane groups -> coalesced-ish */
    float w0[32], w1[32], w2[32];
    {
        const float* base = w_hh + (size_t)(ks * 32) * G3 + col;
#pragma unroll
        for (int j = 0; j < 32; ++j) {
            const float* rp = base + (size_t)j * G3;
            w0[j] = rp[0];
            w1[j] = rp[HH];
            w2[j] = rp[2 * HH];
        }
    }
    /* gate-thread constants */
    float bhr = 0.f, bhz = 0.f, bhn = 0.f;
    if (tid < 128) {
        int c2 = hc0 + (tid & 15);
        bhr = b_hh[c2];
        bhz = b_hh[c2 + HH];
        bhn = b_hh[c2 + 2 * HH];
    }

    unsigned* myflags = flags + (boct << 6); /* 64 uints per octet, 256 B apart */

    /* staging address precompute */
    int sb = tid >> 6;               /* batch 0..7 */
    int sk = (tid & 63) * 16;        /* k 0..1008 */
    int sdst = ((sb << 5) + (sk >> 5)) * 36 + (sk & 31);

    for (int s = 0; s < ct; ++s) {
        int t = t0 + s;
        const float* h_cur = (t & 1) ? hB : hA;
        float* h_nxt = (t & 1) ? hA : hB;

        /* stage h_cur[b0..b0+8][*] -> h_s (coalesced global, padded LDS) */
        {
            const float4* src = (const float4*)(h_cur + (size_t)(b0 + sb) * HH + sk);
            float4* dst = (float4*)&h_s[sdst];
#pragma unroll
            for (int i = 0; i < 4; ++i) dst[i] = src[i];
        }
        __syncthreads();

        /* FMA phase: acc[g][b] over this thread's 32-k slice */
        float acc0[8], acc1[8], acc2[8];
#pragma unroll
        for (int b = 0; b < 8; ++b) {
            const float4* hp = (const float4*)&h_s[((b << 5) + ks) * 36];
            float a0 = 0.f, a1 = 0.f, a2 = 0.f;
#pragma unroll
            for (int q = 0; q < 8; ++q) {
                float4 h4 = hp[q];
                a0 += w0[q * 4 + 0] * h4.x + w0[q * 4 + 1] * h4.y + w0[q * 4 + 2] * h4.z + w0[q * 4 + 3] * h4.w;
                a1 += w1[q * 4 + 0] * h4.x + w1[q * 4 + 1] * h4.y + w1[q * 4 + 2] * h4.z + w1[q * 4 + 3] * h4.w;
                a2 += w2[q * 4 + 0] * h4.x + w2[q * 4 + 1] * h4.y + w2[q * 4 + 2] * h4.z + w2[q * 4 + 3] * h4.w;
            }
            acc0[b] = a0;
            acc1[b] = a1;
            acc2[b] = a2;
        }
        {
            float* pb = &part[cg * 868 + ks];
#pragma unroll
            for (int b = 0; b < 8; ++b) {
                pb[(0 * 8 + b) * 36] = acc0[b];
                pb[(1 * 8 + b) * 36] = acc1[b];
                pb[(2 * 8 + b) * 36] = acc2[b];
            }
        }
        __syncthreads();

        /* k-reduction: 384 threads, one (cg,g,b) each, 8x b128 row reads */
        if (tid < 384) {
            int cgr = tid / 24, rem = tid - cgr * 24;
            const float4* pp = (const float4*)&part[cgr * 868 + rem * 36];
            float4 v = pp[0];
#pragma unroll
            for (int q = 1; q < 8; ++q) {
                float4 u = pp[q];
                v.x += u.x; v.y += u.y; v.z += u.z; v.w += u.w;
            }
            sums[tid] = v.x + v.y + v.z + v.w;
        }
        __syncthreads();

        /* gates: 128 threads, (b2 = tid>>4, c = hc0 + (tid&15)) */
        if (tid < 128) {
            int gcg = tid & 15, b2 = tid >> 4;
            int bg = b0 + b2, c = hc0 + gcg;
            float ghr = sums[gcg * 24 + b2];
            float ghz = sums[gcg * 24 + 8 + b2];
            float ghn = sums[gcg * 24 + 16 + b2];
            const float* gp = gi + ((size_t)s * BB + bg) * G3 + c;
            float gir = gp[0], giz = gp[HH], gin = gp[2 * HH];
            float hprev = h_s[((b2 << 5) + (c >> 5)) * 36 + (c & 31)];
            float p = pad[t * BB + bg];
            float r = sigmoidf_(gir + ghr + bhr);
            float z = sigmoidf_(giz + ghz + bhz);
            float n = tanh_fast(gin + r * (ghn + bhn));
            float hnew = (1.f - z) * n + z * hprev;
            hnew = p * hprev + (1.f - p) * hnew;
            h_nxt[(size_t)bg * HH + c] = hnew;
            size_t oo = (size_t)t * (BB * HH) + (size_t)bg * HH + c;
            out[oo] = hnew;
            out[(size_t)TBH + oo] = hnew;
            __threadfence();
        }
        __syncthreads();

        /* device-wide barrier over the 64 blocks sharing this batch octet */
        if (tid == 0)
            __hip_atomic_store(&myflags[hg], (unsigned)(s + 1), __ATOMIC_RELEASE,
                               __HIP_MEMORY_SCOPE_AGENT);
        if (tid < 64) {
            unsigned tgt = (unsigned)(s + 1);
            for (;;) {
                unsigned f = __hip_atomic_load(&myflags[tid], __ATOMIC_ACQUIRE,
                                               __HIP_MEMORY_SCOPE_AGENT);
                if (__all(f >= tgt)) break;
                __builtin_amdgcn_s_sleep(2);
            }
        }
        __syncthreads();
    }
}

/* ---- emergency fallback if workspace is tiny: fused, slow, correct ---- */
__global__ __launch_bounds__(256) void k_step_slow(const float* __restrict__ x_t,
                                                   const float* __restrict__ pad_t,
                                                   const float* __restrict__ w_ih,
                                                   const float* __restrict__ w_hh,
                                                   const float* __restrict__ b_ih,
                                                   const float* __restrict__ b_hh,
                                                   const float* __restrict__ h_in,
                                                   float* __restrict__ h_out,
                                                   float* __restrict__ out, int t) {
    int g = blockIdx.x * 256 + threadIdx.x;
    int b = g >> 10, j = g & 1023;
    float gir = b_ih[j], giz = b_ih[j + HH], gin = b_ih[j + 2 * HH];
    for (int k = 0; k < II; ++k) {
        float xv = x_t[b * II + k];
        const float* wr = w_ih + (size_t)k * G3;
        gir += xv * wr[j];
        giz += xv * wr[j + HH];
        gin += xv * wr[j + 2 * HH];
    }
    float ghr = b_hh[j], ghz = b_hh[j + HH], ghn = b_hh[j + 2 * HH];
    for (int k = 0; k < HH; ++k) {
        float hv = h_in[b * HH + k];
        const float* wr = w_hh + (size_t)k * G3;
        ghr += hv * wr[j];
        ghz += hv * wr[j + HH];
        ghn += hv * wr[j + 2 * HH];
    }
    float hprev = h_in[b * HH + j];
    float p = pad_t[b];
    float r = sigmoidf_(gir + ghr);
    float z = sigmoidf_(giz + ghz);
    float n = tanh_fast(gin + r * ghn);
    float hnew = (1.f - z) * n + z * hprev;
    hnew = p * hprev + (1.f - p) * hnew;
    size_t o = (size_t)b * HH + j;
    h_out[o] = hnew;
    size_t oo = (size_t)t * (BB * HH) + o;
    out[oo] = hnew;
    out[(size_t)TBH + oo] = hnew;
}

extern "C" void kernel_launch(void* const* d_in, const int* in_sizes, int n_in,
                              void* d_out, int out_size, void* d_ws, size_t ws_size,
                              hipStream_t stream) {
    const float* x    = (const float*)d_in[0];
    const float* pad  = (const float*)d_in[1];
    const float* w_ih = (const float*)d_in[2];
    const float* w_hh = (const float*)d_in[3];
    const float* b_ih = (const float*)d_in[4];
    const float* b_hh = (const float*)d_in[5];
    float* out = (float*)d_out;

    char* wsb = (char*)d_ws;
    float* hA = (float*)wsb;                     /* 128 KB */
    float* hB = (float*)(wsb + 131072);          /* 128 KB */
    unsigned* flags = (unsigned*)(wsb + 262144); /* 1 KB: 4 octets x 64 uints */
    float* gi = (float*)(wsb + 263168);          /* Tc * 32 * 3072 * 4 B */

    long long cap = (long long)ws_size - 263168LL;
    int Tc = cap > 0 ? (int)(cap / 393216LL) : 0;
    if (Tc > TT) Tc = TT;

    hipMemsetAsync(hA, 0, 131072, stream); /* h(t=0) = 0 */

    if (Tc >= 1) {
        for (int t0 = 0; t0 < TT; t0 += Tc) {
            int ctn = (TT - t0 < Tc) ? (TT - t0) : Tc;
            int M = ctn * BB;
            dim3 g((M + 127) / 128, 24);
            k_gi_gemm<<<g, 256, 0, stream>>>(x + (size_t)t0 * BB * II, w_ih, b_ih, gi, M);
            hipMemsetAsync(flags, 0, 1024, stream);
            k_persist<<<256, 512, 0, stream>>>(w_hh, gi, pad, b_hh, hA, hB, out, flags, t0, ctn);
        }
    } else {
        for (int t = 0; t < TT; ++t) {
            const float* hin = (t & 1) ? hB : hA;
            float* hout = (t & 1) ? hA : hB;
            k_step_slow<<<128, 256, 0, stream>>>(x + (size_t)t * BB * II, pad + t * BB,
                                                 w_ih, w_hh, b_ih, b_hh, hin, hout, out, t);
        }
    }
}

// Round 3
// 5404.629 us; speedup vs baseline: 2.4186x; 2.3578x over previous
//
#include <hip/hip_runtime.h>

#define TT 512
#define BB 32
#define II 512
#define HH 1024
#define G3 3072
#define TBH (TT * BB * HH) /* 16777216 */

__device__ __forceinline__ float sigmoidf_(float x) {
    return 1.f / (1.f + __expf(-x));
}
__device__ __forceinline__ float tanh_fast(float x) {
    float e2 = __expf(2.f * x);
    return 1.f - 2.f / (e2 + 1.f);
}

/* ---- gi = A(M x 512) @ w_ih(512 x 3072) + b_ih ---- */
__global__ __launch_bounds__(256) void k_gi_gemm(const float* __restrict__ A,
                                                 const float* __restrict__ B,
                                                 const float* __restrict__ bias,
                                                 float* __restrict__ C, int M) {
    __shared__ float As[8][128];
    __shared__ float Bs[8][128];
    int tid = threadIdx.x;
    int m0 = blockIdx.x * 128;
    int n0 = blockIdx.y * 128;
    int tx = tid & 15, ty = tid >> 4;
    int rowA = tid >> 1, kA = (tid & 1) * 4;
    int kB = tid >> 5, cB = (tid & 31) * 4;
    float acc[8][8] = {};
    for (int k0 = 0; k0 < 512; k0 += 8) {
        int rg = m0 + rowA;
        if (rg > M - 1) rg = M - 1;
        float4 a4 = *(const float4*)(A + (size_t)rg * 512 + k0 + kA);
        float4 b4 = *(const float4*)(B + (size_t)(k0 + kB) * G3 + n0 + cB);
        __syncthreads();
        As[kA + 0][rowA] = a4.x;
        As[kA + 1][rowA] = a4.y;
        As[kA + 2][rowA] = a4.z;
        As[kA + 3][rowA] = a4.w;
        *(float4*)&Bs[kB][cB] = b4;
        __syncthreads();
#pragma unroll
        for (int kk = 0; kk < 8; ++kk) {
            float4 a0 = *(const float4*)&As[kk][ty * 8];
            float4 a1 = *(const float4*)&As[kk][ty * 8 + 4];
            float4 b0 = *(const float4*)&Bs[kk][tx * 8];
            float4 b1 = *(const float4*)&Bs[kk][tx * 8 + 4];
            float av[8] = {a0.x, a0.y, a0.z, a0.w, a1.x, a1.y, a1.z, a1.w};
            float bv[8] = {b0.x, b0.y, b0.z, b0.w, b1.x, b1.y, b1.z, b1.w};
#pragma unroll
            for (int i = 0; i < 8; ++i)
#pragma unroll
                for (int j = 0; j < 8; ++j) acc[i][j] += av[i] * bv[j];
        }
    }
    float4 bi0 = *(const float4*)(bias + n0 + tx * 8);
    float4 bi1 = *(const float4*)(bias + n0 + tx * 8 + 4);
    float bb[8] = {bi0.x, bi0.y, bi0.z, bi0.w, bi1.x, bi1.y, bi1.z, bi1.w};
#pragma unroll
    for (int i = 0; i < 8; ++i) {
        int row = m0 + ty * 8 + i;
        if (row < M) {
            float4 s0 = {acc[i][0] + bb[0], acc[i][1] + bb[1], acc[i][2] + bb[2], acc[i][3] + bb[3]};
            float4 s1 = {acc[i][4] + bb[4], acc[i][5] + bb[5], acc[i][6] + bb[6], acc[i][7] + bb[7]};
            *(float4*)(C + (size_t)row * G3 + n0 + tx * 8) = s0;
            *(float4*)(C + (size_t)row * G3 + n0 + tx * 8 + 4) = s1;
        }
    }
}

/* ---- persistent recurrent kernel ----
   grid 256 = 64 h-col-groups x 4 batch-octets; block 512 thr = 8 waves.
   All cross-block traffic (h ping-pong, flags) uses RELAXED agent-scope
   atomics: sc0+sc1 ops go straight to L3, no buffer_inv / wbl2 cache-wide
   ops ever (the acquire-per-poll L2 invalidates were R2's 19us/step stall).
   Ordering: h stores -> s_waitcnt vmcnt(0) (all thr) -> barrier -> flag
   store; readers poll relaxed, then compiler barrier, then load h via sc
   atomics (fresh from L3 by construction). */
__global__ __launch_bounds__(512, 2) void k_persist(const float* __restrict__ w_hh,
                                                    const float* __restrict__ gi,
                                                    const float* __restrict__ pad,
                                                    const float* __restrict__ b_hh,
                                                    float* __restrict__ hA,
                                                    float* __restrict__ hB,
                                                    float* __restrict__ out,
                                                    unsigned* __restrict__ flags,
                                                    int t0, int ct) {
    __shared__ float h_s[9216];   /* [b 8][row 32] rows of 36 (32 + 4 pad) */
    __shared__ float part[13888]; /* [cg 16] stride 868: [(g,b) 24] stride 36: [ks 32] */

    int tid = threadIdx.x;
    int cg = tid & 15, ks = tid >> 4;
    int hg = blockIdx.x & 63, boct = blockIdx.x >> 6;
    int hc0 = hg << 4;
    int b0 = boct << 3;
    int col = hc0 + cg;

    /* one-time weight load into float4 regs */
    float4 w0q[8], w1q[8], w2q[8];
    {
        const float* wb = w_hh + (size_t)(ks * 32) * G3 + col;
#pragma unroll
        for (int j = 0; j < 8; ++j) {
            w0q[j].x = wb[(j * 4 + 0) * G3];
            w0q[j].y = wb[(j * 4 + 1) * G3];
            w0q[j].z = wb[(j * 4 + 2) * G3];
            w0q[j].w = wb[(j * 4 + 3) * G3];
            w1q[j].x = wb[(j * 4 + 0) * G3 + HH];
            w1q[j].y = wb[(j * 4 + 1) * G3 + HH];
            w1q[j].z = wb[(j * 4 + 2) * G3 + HH];
            w1q[j].w = wb[(j * 4 + 3) * G3 + HH];
            w2q[j].x = wb[(j * 4 + 0) * G3 + 2 * HH];
            w2q[j].y = wb[(j * 4 + 1) * G3 + 2 * HH];
            w2q[j].z = wb[(j * 4 + 2) * G3 + 2 * HH];
            w2q[j].w = wb[(j * 4 + 3) * G3 + 2 * HH];
        }
    }
    /* gate-thread constants (tid<128: gcg=cg, b2=tid>>4) */
    int b2 = tid >> 4;
    int bg = b0 + b2;
    float bhr = 0.f, bhz = 0.f, bhn = 0.f;
    if (tid < 128) {
        bhr = b_hh[col];
        bhz = b_hh[col + HH];
        bhn = b_hh[col + 2 * HH];
    }

    unsigned* myflags = flags + (boct << 6);

    /* staging geometry: wave sb stages batch sb; 8x 8-byte relaxed atomic
       loads per thread, lane-contiguous (512 B/instr coalesced) */
    int sb = tid >> 6;
    int lane = tid & 63;
    int srow0 = lane >> 4;
    int scol = (lane & 15) * 2;

    for (int s = 0; s < ct; ++s) {
        int t = t0 + s;
        const float* h_cur = (t & 1) ? hB : hA;
        float* h_nxt = (t & 1) ? hA : hB;

        /* prefetch gi + pad for this step (consumed in gates phase) */
        float gir = 0.f, giz = 0.f, gin = 0.f, pv = 0.f;
        if (tid < 128) {
            const float* gp = gi + ((size_t)s * BB + bg) * G3 + col;
            gir = gp[0];
            giz = gp[HH];
            gin = gp[2 * HH];
            pv = pad[t * BB + bg];
        }

        /* stage h_cur -> h_s via relaxed agent atomics (bypass L1/L2) */
        {
            const unsigned long long* hp =
                (const unsigned long long*)(h_cur + (size_t)(b0 + sb) * HH) + lane;
#pragma unroll
            for (int i = 0; i < 8; ++i) {
                unsigned long long v = __hip_atomic_load(hp + i * 64, __ATOMIC_RELAXED,
                                                         __HIP_MEMORY_SCOPE_AGENT);
                *(unsigned long long*)&h_s[((sb << 5) + 4 * i + srow0) * 36 + scol] = v;
            }
        }
        __syncthreads();

        /* FMA phase */
        float acc0[8], acc1[8], acc2[8];
#pragma unroll
        for (int b = 0; b < 8; ++b) {
            const float4* hp4 = (const float4*)&h_s[((b << 5) + ks) * 36];
            float a0 = 0.f, a1 = 0.f, a2 = 0.f;
#pragma unroll
            for (int q = 0; q < 8; ++q) {
                float4 h4 = hp4[q];
                a0 += w0q[q].x * h4.x + w0q[q].y * h4.y + w0q[q].z * h4.z + w0q[q].w * h4.w;
                a1 += w1q[q].x * h4.x + w1q[q].y * h4.y + w1q[q].z * h4.z + w1q[q].w * h4.w;
                a2 += w2q[q].x * h4.x + w2q[q].y * h4.y + w2q[q].z * h4.z + w2q[q].w * h4.w;
            }
            acc0[b] = a0;
            acc1[b] = a1;
            acc2[b] = a2;
        }
        {
            float* pb = &part[cg * 868 + ks];
#pragma unroll
            for (int b = 0; b < 8; ++b) {
                pb[b * 36] = acc0[b];
                pb[(8 + b) * 36] = acc1[b];
                pb[(16 + b) * 36] = acc2[b];
            }
        }
        __syncthreads();

        /* gates: 128 threads each reduce their own 3 partial rows */
        float hnew = 0.f;
        size_t oo = 0;
        if (tid < 128) {
            float gh0, gh1, gh2;
#pragma unroll
            for (int g = 0; g < 3; ++g) {
                const float4* pp = (const float4*)&part[cg * 868 + (g * 8 + b2) * 36];
                float4 v = pp[0];
#pragma unroll
                for (int q = 1; q < 8; ++q) {
                    float4 u = pp[q];
                    v.x += u.x; v.y += u.y; v.z += u.z; v.w += u.w;
                }
                float sv = v.x + v.y + v.z + v.w;
                if (g == 0) gh0 = sv;
                else if (g == 1) gh1 = sv;
                else gh2 = sv;
            }
            float hprev = h_s[((b2 << 5) + (col >> 5)) * 36 + (col & 31)];
            float r = sigmoidf_(gir + gh0 + bhr);
            float z = sigmoidf_(giz + gh1 + bhz);
            float n = tanh_fast(gin + r * (gh2 + bhn));
            hnew = (1.f - z) * n + z * hprev;
            hnew = pv * hprev + (1.f - pv) * hnew;
            __hip_atomic_store(h_nxt + (size_t)bg * HH + col, hnew, __ATOMIC_RELAXED,
                               __HIP_MEMORY_SCOPE_AGENT);
            oo = (size_t)t * (BB * HH) + (size_t)bg * HH + col;
        }
        /* drain h stores to L3 before signalling */
        asm volatile("s_waitcnt vmcnt(0)" ::: "memory");
        __syncthreads();
        if (tid == 0)
            __hip_atomic_store(&myflags[hg], (unsigned)(s + 1), __ATOMIC_RELAXED,
                               __HIP_MEMORY_SCOPE_AGENT);
        /* out writes overlap the poll wait */
        if (tid < 128) {
            out[oo] = hnew;
            out[(size_t)TBH + oo] = hnew;
        }
        if (tid < 64) {
            unsigned tgt = (unsigned)(s + 1);
            for (;;) {
                unsigned f = __hip_atomic_load(&myflags[tid], __ATOMIC_RELAXED,
                                               __HIP_MEMORY_SCOPE_AGENT);
                if (__all(f >= tgt)) break;
                __builtin_amdgcn_s_sleep(1);
            }
        }
        asm volatile("" ::: "memory");
        __syncthreads();
    }
}

/* ---- emergency fallback if workspace is tiny: fused, slow, correct ---- */
__global__ __launch_bounds__(256) void k_step_slow(const float* __restrict__ x_t,
                                                   const float* __restrict__ pad_t,
                                                   const float* __restrict__ w_ih,
                                                   const float* __restrict__ w_hh,
                                                   const float* __restrict__ b_ih,
                                                   const float* __restrict__ b_hh,
                                                   const float* __restrict__ h_in,
                                                   float* __restrict__ h_out,
                                                   float* __restrict__ out, int t) {
    int g = blockIdx.x * 256 + threadIdx.x;
    int b = g >> 10, j = g & 1023;
    float gir = b_ih[j], giz = b_ih[j + HH], gin = b_ih[j + 2 * HH];
    for (int k = 0; k < II; ++k) {
        float xv = x_t[b * II + k];
        const float* wr = w_ih + (size_t)k * G3;
        gir += xv * wr[j];
        giz += xv * wr[j + HH];
        gin += xv * wr[j + 2 * HH];
    }
    float ghr = b_hh[j], ghz = b_hh[j + HH], ghn = b_hh[j + 2 * HH];
    for (int k = 0; k < HH; ++k) {
        float hv = h_in[b * HH + k];
        const float* wr = w_hh + (size_t)k * G3;
        ghr += hv * wr[j];
        ghz += hv * wr[j + HH];
        ghn += hv * wr[j + 2 * HH];
    }
    float hprev = h_in[b * HH + j];
    float p = pad_t[b];
    float r = sigmoidf_(gir + ghr);
    float z = sigmoidf_(giz + ghz);
    float n = tanh_fast(gin + r * ghn);
    float hnew = (1.f - z) * n + z * hprev;
    hnew = p * hprev + (1.f - p) * hnew;
    size_t o = (size_t)b * HH + j;
    h_out[o] = hnew;
    size_t oo = (size_t)t * (BB * HH) + o;
    out[oo] = hnew;
    out[(size_t)TBH + oo] = hnew;
}

extern "C" void kernel_launch(void* const* d_in, const int* in_sizes, int n_in,
                              void* d_out, int out_size, void* d_ws, size_t ws_size,
                              hipStream_t stream) {
    const float* x    = (const float*)d_in[0];
    const float* pad  = (const float*)d_in[1];
    const float* w_ih = (const float*)d_in[2];
    const float* w_hh = (const float*)d_in[3];
    const float* b_ih = (const float*)d_in[4];
    const float* b_hh = (const float*)d_in[5];
    float* out = (float*)d_out;

    char* wsb = (char*)d_ws;
    float* hA = (float*)wsb;                     /* 128 KB */
    float* hB = (float*)(wsb + 131072);          /* 128 KB */
    unsigned* flags = (unsigned*)(wsb + 262144); /* 1 KB: 4 octets x 64 uints */
    float* gi = (float*)(wsb + 263168);          /* Tc * 32 * 3072 * 4 B */

    long long cap = (long long)ws_size - 263168LL;
    int Tc = cap > 0 ? (int)(cap / 393216LL) : 0;
    if (Tc > TT) Tc = TT;

    hipMemsetAsync(hA, 0, 131072, stream); /* h(t=0) = 0 */

    if (Tc >= 1) {
        for (int t0 = 0; t0 < TT; t0 += Tc) {
            int ctn = (TT - t0 < Tc) ? (TT - t0) : Tc;
            int M = ctn * BB;
            dim3 g((M + 127) / 128, 24);
            k_gi_gemm<<<g, 256, 0, stream>>>(x + (size_t)t0 * BB * II, w_ih, b_ih, gi, M);
            hipMemsetAsync(flags, 0, 1024, stream);
            k_persist<<<256, 512, 0, stream>>>(w_hh, gi, pad, b_hh, hA, hB, out, flags, t0, ctn);
        }
    } else {
        for (int t = 0; t < TT; ++t) {
            const float* hin = (t & 1) ? hB : hA;
            float* hout = (t & 1) ? hA : hB;
            k_step_slow<<<128, 256, 0, stream>>>(x + (size_t)t * BB * II, pad + t * BB,
                                                 w_ih, w_hh, b_ih, b_hh, hin, hout, out, t);
        }
    }
}